// Round 14
// baseline (238.283 us; speedup 1.0000x reference)
//
#include <hip/hip_runtime.h>

#define N_NODES 50000
#define N_EDGES 800000
#define D 128
#define NBKT 196        // ceil(50000/256) dst-buckets of 256 nodes
#define BKT_CAP 5120    // mean 4082, sigma ~64 -> +16 sigma headroom

typedef __attribute__((ext_vector_type(8))) short bf16x8;
typedef __attribute__((ext_vector_type(4))) float f32x4;
typedef __attribute__((ext_vector_type(4))) uint uint4v;

__device__ __forceinline__ float bf2f(unsigned short u) {
    unsigned int x = ((unsigned int)u) << 16;
    return __builtin_bit_cast(float, x);
}
__device__ __forceinline__ unsigned short f2bf(float f) {
    unsigned int u = __builtin_bit_cast(unsigned int, f);
    unsigned int r = (u + 0x7fffu + ((u >> 16) & 1u)) >> 16;   // RNE
    return (unsigned short)r;
}

// ---------------- CSR build: bucket partition + LDS counting sort ----------

__global__ __launch_bounds__(256) void k_part(const int* __restrict__ ei,
                                              int* __restrict__ bcnt,
                                              uint* __restrict__ bucket) {
    __shared__ int hist[NBKT];
    __shared__ int base[NBKT];
    int tid = threadIdx.x;
    for (int i = tid; i < NBKT; i += 256) hist[i] = 0;
    __syncthreads();
    int e0 = blockIdx.x * 2048;
    uint meta[8];
    #pragma unroll
    for (int i = 0; i < 8; ++i) {
        int e = e0 + i * 256 + tid;
        uint m = 0xFFFFFFFFu;
        if (e < N_EDGES) {
            int dst = ei[N_EDGES + e];
            int b = dst >> 8;
            int dl = dst & 255;
            int r = atomicAdd(&hist[b], 1);          // rank within block's chunk
            m = ((uint)b << 21) | ((uint)dl << 13) | (uint)r;   // r < 2048 < 2^13
        }
        meta[i] = m;
    }
    __syncthreads();
    for (int i = tid; i < NBKT; i += 256)
        base[i] = hist[i] ? atomicAdd(&bcnt[i], hist[i]) : 0;
    __syncthreads();
    #pragma unroll
    for (int i = 0; i < 8; ++i) {
        int e = e0 + i * 256 + tid;
        if (e < N_EDGES) {
            uint m = meta[i];
            int b = (int)(m >> 21);
            int dl = (int)((m >> 13) & 255);
            int r = (int)(m & 8191);
            int src = ei[e];
            int pos = base[b] + r;
            if (pos < BKT_CAP)
                bucket[(size_t)b * BKT_CAP + pos] = ((uint)dl << 16) | (uint)src;
        }
    }
}

// per-bucket histogram -> deg (coalesced write)
__global__ __launch_bounds__(256) void k_hist(const int* __restrict__ bcnt,
                                              const uint* __restrict__ bucket,
                                              int* __restrict__ deg) {
    __shared__ int hist[256];
    int b = blockIdx.x, tid = threadIdx.x;
    hist[tid] = 0;
    __syncthreads();
    int n = bcnt[b]; if (n > BKT_CAP) n = BKT_CAP;
    for (int i = tid; i < n; i += 256)
        atomicAdd(&hist[(bucket[(size_t)b * BKT_CAP + i] >> 16) & 255], 1);
    __syncthreads();
    int node = b * 256 + tid;
    if (node < N_NODES) deg[node] = hist[tid];
}

// hierarchical exclusive scan of deg[50000] -> rowp
__global__ __launch_bounds__(256) void k_scan1(const int* __restrict__ deg,
                                               int* __restrict__ rowp,
                                               int* __restrict__ bsum) {
    __shared__ int s[256];
    int t = threadIdx.x;
    int i = blockIdx.x * 256 + t;
    int v = (i < N_NODES) ? deg[i] : 0;
    s[t] = v;
    __syncthreads();
    for (int off = 1; off < 256; off <<= 1) {
        int u = (t >= off) ? s[t - off] : 0;
        __syncthreads();
        s[t] += u;
        __syncthreads();
    }
    if (i < N_NODES) rowp[i] = s[t] - v;
    if (t == 255) bsum[blockIdx.x] = s[255];
}

__global__ __launch_bounds__(256) void k_scan2(int* __restrict__ bsum, int nb) {
    __shared__ int s[256];
    int t = threadIdx.x;
    int v = (t < nb) ? bsum[t] : 0;
    s[t] = v;
    __syncthreads();
    for (int off = 1; off < 256; off <<= 1) {
        int u = (t >= off) ? s[t - off] : 0;
        __syncthreads();
        s[t] += u;
        __syncthreads();
    }
    if (t < nb) bsum[t] = s[t] - v;
}

__global__ __launch_bounds__(256) void k_scan3(int* __restrict__ rowp,
                                               const int* __restrict__ bsum) {
    int i = blockIdx.x * 256 + threadIdx.x;
    if (i < N_NODES) rowp[i] += bsum[blockIdx.x];
    if (i == 0) rowp[N_NODES] = N_EDGES;
}

// per-bucket counting sort -> colx (writes land in contiguous region)
__global__ __launch_bounds__(256) void k_sort(const int* __restrict__ bcnt,
                                              const uint* __restrict__ bucket,
                                              const int* __restrict__ rowp,
                                              int* __restrict__ colx) {
    __shared__ int fil[256];
    __shared__ int rp[256];
    int b = blockIdx.x, tid = threadIdx.x;
    fil[tid] = 0;
    int node = b * 256 + tid;
    rp[tid] = (node < N_NODES) ? rowp[node] : 0;
    __syncthreads();
    int n = bcnt[b]; if (n > BKT_CAP) n = BKT_CAP;
    for (int i = tid; i < n; i += 256) {
        uint w = bucket[(size_t)b * BKT_CAP + i];
        int dl = (int)((w >> 16) & 255);
        int src = (int)(w & 0xFFFF);
        int p = rp[dl] + atomicAdd(&fil[dl], 1);
        colx[p] = src;
    }
}

// ---------------- fp32 -> bf16 + fp8 conversions ----------------

__global__ __launch_bounds__(256) void k_cvt(const float* __restrict__ in,
                                             ushort* __restrict__ outb,
                                             uint* __restrict__ outq, int n4) {
    int i = blockIdx.x * 256 + threadIdx.x;
    if (i >= n4) return;
    float4 v = ((const float4*)in)[i];
    ushort4 o;
    o.x = f2bf(v.x); o.y = f2bf(v.y); o.z = f2bf(v.z); o.w = f2bf(v.w);
    ((ushort4*)outb)[i] = o;
    int q = __builtin_amdgcn_cvt_pk_fp8_f32(v.x, v.y, 0, false);
    q = __builtin_amdgcn_cvt_pk_fp8_f32(v.z, v.w, q, true);
    outq[i] = (uint)q;
}

__global__ __launch_bounds__(256) void k_cvtw(const float* __restrict__ w0,
                                              const float* __restrict__ w1,
                                              const float* __restrict__ w2,
                                              const float* __restrict__ w3,
                                              ushort* o0, ushort* o1,
                                              ushort* o2, ushort* o3) {
    int b = blockIdx.x >> 4;                        // which W (4096 float4 each)
    int i = (blockIdx.x & 15) * 256 + threadIdx.x;  // float4 index
    const float* in = (b == 0) ? w0 : (b == 1) ? w1 : (b == 2) ? w2 : w3;
    ushort*     out = (b == 0) ? o0 : (b == 1) ? o1 : (b == 2) ? o2 : o3;
    float4 v = ((const float4*)in)[i];
    ushort4 o;
    o.x = f2bf(v.x); o.y = f2bf(v.y); o.z = f2bf(v.z); o.w = f2bf(v.w);
    ((ushort4*)out)[i] = o;
}

// bf16 h1 -> fp8 h1 (for layer-2 gather); 8 values per thread
__global__ __launch_bounds__(256) void k_cvt8(const ushort* __restrict__ inb,
                                              uint* __restrict__ outq, int n8) {
    int i = blockIdx.x * 256 + threadIdx.x;
    if (i >= n8) return;
    bf16x8 v = ((const bf16x8*)inb)[i];
    float f0 = bf2f((unsigned short)v[0]), f1 = bf2f((unsigned short)v[1]);
    float f2 = bf2f((unsigned short)v[2]), f3 = bf2f((unsigned short)v[3]);
    float f4 = bf2f((unsigned short)v[4]), f5 = bf2f((unsigned short)v[5]);
    float f6 = bf2f((unsigned short)v[6]), f7 = bf2f((unsigned short)v[7]);
    int q0 = __builtin_amdgcn_cvt_pk_fp8_f32(f0, f1, 0, false);
    q0 = __builtin_amdgcn_cvt_pk_fp8_f32(f2, f3, q0, true);
    int q1 = __builtin_amdgcn_cvt_pk_fp8_f32(f4, f5, 0, false);
    q1 = __builtin_amdgcn_cvt_pk_fp8_f32(f6, f7, q1, true);
    uint2 o; o.x = (uint)q0; o.y = (uint)q1;
    ((uint2*)outq)[i] = o;
}

// ------- mean aggregation, HALF-ROW passes (L2-resident 3.2MB slice) --------
// phase p gathers bytes [p*64, p*64+64) of each fp8 row -> working set = the
// even (p=0) / odd (p=1) 64B lines only = 3.2 MB, fits per-XCD L2 (4 MB).
// 8 lanes/node: sl=0..3 16B slot in half-row; lanes 0-3 even edges, 4-7 odd.
// Mb stores are non-temporal so the output stream doesn't evict the slice.

__device__ __forceinline__ void acc4(float* a, unsigned int word) {
    a[0] += __builtin_amdgcn_cvt_f32_fp8(word, 0);
    a[1] += __builtin_amdgcn_cvt_f32_fp8(word, 1);
    a[2] += __builtin_amdgcn_cvt_f32_fp8(word, 2);
    a[3] += __builtin_amdgcn_cvt_f32_fp8(word, 3);
}
__device__ __forceinline__ void acc16(float* a, uint4 v) {
    acc4(a + 0, v.x); acc4(a + 4, v.y); acc4(a + 8, v.z); acc4(a + 12, v.w);
}

__global__ __launch_bounds__(256) void k_aggh(const uint* __restrict__ Xq,
                                              const int* __restrict__ rowp,
                                              const int* __restrict__ colx,
                                              ushort* __restrict__ Mb,
                                              int phase) {
    int t = blockIdx.x * 256 + threadIdx.x;
    int node = t >> 3;
    int sl = threadIdx.x & 3;           // 16B slot within 64B half-row
    int half = (threadIdx.x >> 2) & 1;  // even/odd edge stream
    if (node >= N_NODES) return;
    int beg = rowp[node], end = rowp[node + 1];
    const uint* base = Xq + phase * 16 + sl * 4;   // phase*64B + sl*16B
    float a[16];
    #pragma unroll
    for (int q = 0; q < 16; ++q) a[q] = 0.f;
    int j = beg + half;
    for (; j + 6 < end; j += 8) {                    // 4 edges per stream
        int s0 = colx[j], s1 = colx[j + 2], s2 = colx[j + 4], s3 = colx[j + 6];
        uint4 w0 = *(const uint4*)(base + (size_t)s0 * 32);
        uint4 w1 = *(const uint4*)(base + (size_t)s1 * 32);
        uint4 w2 = *(const uint4*)(base + (size_t)s2 * 32);
        uint4 w3 = *(const uint4*)(base + (size_t)s3 * 32);
        acc16(a, w0); acc16(a, w1); acc16(a, w2); acc16(a, w3);
    }
    for (; j < end; j += 2) {
        int s0 = colx[j];
        uint4 w0 = *(const uint4*)(base + (size_t)s0 * 32);
        acc16(a, w0);
    }
    #pragma unroll
    for (int q = 0; q < 16; ++q) a[q] += __shfl_xor(a[q], 4, 64);
    if (half == 0) {
        float inv = 1.0f / fmaxf((float)(end - beg), 1.0f);
        bf16x8 o0, o1;
        #pragma unroll
        for (int q = 0; q < 8; ++q) o0[q] = (short)f2bf(a[q] * inv);
        #pragma unroll
        for (int q = 0; q < 8; ++q) o1[q] = (short)f2bf(a[q + 8] * inv);
        ushort* dst = Mb + (size_t)node * D + phase * 64 + sl * 16;
        __builtin_nontemporal_store(__builtin_bit_cast(uint4v, o0), (uint4v*)dst);
        __builtin_nontemporal_store(__builtin_bit_cast(uint4v, o1), (uint4v*)(dst + 8));
    }
}

// ---------------- MFMA GEMM: W staged in swizzled LDS ----------------
// Wcat = [Wl | Wr] as [128 outcols][256 k'] bf16; swizzle byte ^= (row&7)<<4.
// A-frag: lane holds A[l&15][(l>>4)*8+j]; C/D: row=4*(l>>4)+i, col=16c+(l&15).
// mode 0: h1 = leaky(norm(...)) -> h1b.  mode 1: out = norm(...) + bf2f(h1b).

__global__ __launch_bounds__(256) void k_gemm(const ushort* __restrict__ Ab_m,
                                              const ushort* __restrict__ Ab_x,
                                              const ushort* __restrict__ Wl,
                                              const ushort* __restrict__ Wr,
                                              const float* __restrict__ bias,
                                              const ushort* __restrict__ h1b_in,
                                              float* __restrict__ out,
                                              ushort* __restrict__ h1b_out,
                                              int mode) {
    __shared__ ushort Wlds[32768];     // 64 KB
    int tid = threadIdx.x;

    #pragma unroll
    for (int jj = 0; jj < 16; ++jj) {
        int n = jj * 256 + tid;
        int row = n >> 5, c16 = n & 31;
        const ushort* src = (c16 < 16) ? (Wl + row * 128 + c16 * 8)
                                       : (Wr + row * 128 + (c16 - 16) * 8);
        bf16x8 v = *(const bf16x8*)src;
        int slot = row * 32 + (c16 ^ (row & 7));
        *(bf16x8*)(Wlds + slot * 8) = v;
    }
    __syncthreads();

    int lane = tid & 63;
    int wid = tid >> 6;
    int r = lane & 15, g = lane >> 4;
    int row0 = blockIdx.x * 64 + wid * 16;
    int anode = row0 + r;
    bool avalid = anode < N_NODES;
    const ushort* am = Ab_m + (size_t)anode * D + g * 8;
    const ushort* ax = Ab_x + (size_t)anode * D + g * 8;

    f32x4 acc[8];
    #pragma unroll
    for (int c = 0; c < 8; ++c) acc[c] = (f32x4){0.f, 0.f, 0.f, 0.f};

    #pragma unroll
    for (int s = 0; s < 8; ++s) {
        bf16x8 a = (bf16x8){0, 0, 0, 0, 0, 0, 0, 0};
        if (avalid) a = *(const bf16x8*)((s < 4 ? am : ax) + (s & 3) * 32);
        #pragma unroll
        for (int c = 0; c < 8; ++c) {
            int wrow = c * 16 + r;
            int byte = (wrow * 512 + s * 64 + g * 16) ^ ((wrow & 7) << 4);
            bf16x8 b = *(const bf16x8*)((const char*)Wlds + byte);
            acc[c] = __builtin_amdgcn_mfma_f32_16x16x32_bf16(a, b, acc[c], 0, 0, 0);
        }
    }

    #pragma unroll
    for (int c = 0; c < 8; ++c) {
        float bv = bias[c * 16 + r];
        #pragma unroll
        for (int i = 0; i < 4; ++i) acc[c][i] += bv;
    }

    float ss[4];
    #pragma unroll
    for (int i = 0; i < 4; ++i) {
        float s = 0.f;
        #pragma unroll
        for (int c = 0; c < 8; ++c) s += acc[c][i] * acc[c][i];
        ss[i] = s;
    }
    #pragma unroll
    for (int m = 1; m < 16; m <<= 1) {
        #pragma unroll
        for (int i = 0; i < 4; ++i) ss[i] += __shfl_xor(ss[i], m, 64);
    }
    float rn[4];
    #pragma unroll
    for (int i = 0; i < 4; ++i) rn[i] = 1.0f / fmaxf(sqrtf(ss[i]), 1e-12f);

    #pragma unroll
    for (int i = 0; i < 4; ++i) {
        int row = row0 + 4 * g + i;
        if (row >= N_NODES) continue;
        #pragma unroll
        for (int c = 0; c < 8; ++c) {
            int col = c * 16 + r;
            float v = acc[c][i] * rn[i];
            if (mode == 0) {
                v = (v > 0.f) ? v : 0.01f * v;               // leaky_relu
                h1b_out[(size_t)row * D + col] = f2bf(v);
            } else {
                v += bf2f(h1b_in[(size_t)row * D + col]);     // h1 + h2
                out[(size_t)row * D + col] = v;
            }
        }
    }
}

// ---------------- launch ----------------

extern "C" void kernel_launch(void* const* d_in, const int* in_sizes, int n_in,
                              void* d_out, int out_size, void* d_ws, size_t ws_size,
                              hipStream_t stream) {
    const float* x   = (const float*)d_in[0];
    const int*   ei  = (const int*)d_in[1];   // int64 in ref, JAX x64-off => int32
    const float* W1l = (const float*)d_in[2];
    const float* b1l = (const float*)d_in[3];
    const float* W1r = (const float*)d_in[4];
    const float* W2l = (const float*)d_in[5];
    const float* b2l = (const float*)d_in[6];
    const float* W2r = (const float*)d_in[7];
    float* out = (float*)d_out;
    char*  ws  = (char*)d_ws;

    // workspace layout (bytes), total ~40 MB
    int*    bcnt = (int*)(ws + 0);              // 784 B   (zeroed each call)
    int*    deg  = (int*)(ws + 1024);           // 200000
    int*    rowp = (int*)(ws + 204800);         // 200004
    int*    colx = (int*)(ws + 409600);         // 3.2 MB
    ushort* xb   = (ushort*)(ws + 3609600);     // 12.8 MB (becomes h1b after L1)
    ushort* Mb   = (ushort*)(ws + 16409600);    // 12.8 MB (mean buffer)
    ushort* Wb   = (ushort*)(ws + 29209600);    // 128 KB  (4x bf16 weights)
    ushort* W1lb = Wb;
    ushort* W1rb = Wb + 16384;
    ushort* W2lb = Wb + 32768;
    ushort* W2rb = Wb + 49152;
    int*    bsum = (int*)(ws + 29340672);       // 784 B (196 block sums)
    uint*   Q    = (uint*)(ws + 29341696);      // 6.4 MB fp8 table (x, then h1)
    uint*   bkt  = (uint*)(ws + 35742208);      // 4.0 MB bucket payload

    hipMemsetAsync(bcnt, 0, 1024, stream);      // bucket counters only

    k_cvt <<<6250, 256, 0, stream>>>(x, xb, Q, (N_NODES * D) / 4);
    k_cvtw<<<64, 256, 0, stream>>>(W1l, W1r, W2l, W2r, W1lb, W1rb, W2lb, W2rb);

    const int NB = (N_NODES + 255) / 256;       // 196
    k_part<<<(N_EDGES + 2047) / 2048, 256, 0, stream>>>(ei, bcnt, bkt);
    k_hist<<<NBKT, 256, 0, stream>>>(bcnt, bkt, deg);
    k_scan1<<<NB, 256, 0, stream>>>(deg, rowp, bsum);
    k_scan2<<<1, 256, 0, stream>>>(bsum, NB);
    k_scan3<<<NB, 256, 0, stream>>>(rowp, bsum);
    k_sort<<<NBKT, 256, 0, stream>>>(bcnt, bkt, rowp, colx);

    const int NH = (N_NODES * 8 + 255) / 256;   // 1563
    // layer 1: gather x (fp8, two L2-resident half passes); h1 bf16 -> xb
    k_aggh<<<NH, 256, 0, stream>>>(Q, rowp, colx, Mb, 0);
    k_aggh<<<NH, 256, 0, stream>>>(Q, rowp, colx, Mb, 1);
    k_gemm<<<(N_NODES + 63) / 64, 256, 0, stream>>>(Mb, xb, W1lb, W1rb, b1l,
                                                    nullptr, out, xb, 0);
    // h1 bf16 -> fp8 table (overwrites x-fp8, safe: layer-1 agg done)
    k_cvt8<<<(N_NODES * D / 8 + 255) / 256, 256, 0, stream>>>(xb, Q, N_NODES * D / 8);
    // layer 2: gather h1 (fp8); out = bf2f(h1b) + h2
    k_aggh<<<NH, 256, 0, stream>>>(Q, rowp, colx, Mb, 0);
    k_aggh<<<NH, 256, 0, stream>>>(Q, rowp, colx, Mb, 1);
    k_gemm<<<(N_NODES + 63) / 64, 256, 0, stream>>>(Mb, xb, W2lb, W2rb, b2l,
                                                    xb, out, nullptr, 1);
}

// Round 15
// 205.371 us; speedup vs baseline: 1.1603x; 1.1603x over previous
//
#include <hip/hip_runtime.h>

#define N_NODES 50000
#define N_EDGES 800000
#define D 128
#define NBKT 196        // ceil(50000/256) dst-buckets of 256 nodes
#define BKT_CAP 5120    // mean 4082, sigma ~64 -> +16 sigma headroom

typedef __attribute__((ext_vector_type(8))) short bf16x8;
typedef __attribute__((ext_vector_type(4))) float f32x4;

__device__ __forceinline__ float bf2f(unsigned short u) {
    unsigned int x = ((unsigned int)u) << 16;
    return __builtin_bit_cast(float, x);
}
__device__ __forceinline__ unsigned short f2bf(float f) {
    unsigned int u = __builtin_bit_cast(unsigned int, f);
    unsigned int r = (u + 0x7fffu + ((u >> 16) & 1u)) >> 16;   // RNE
    return (unsigned short)r;
}

// ---------------- CSR build: bucket partition + LDS counting sort ----------

__global__ __launch_bounds__(256) void k_part(const int* __restrict__ ei,
                                              int* __restrict__ bcnt,
                                              uint* __restrict__ bucket) {
    __shared__ int hist[NBKT];
    __shared__ int base[NBKT];
    int tid = threadIdx.x;
    for (int i = tid; i < NBKT; i += 256) hist[i] = 0;
    __syncthreads();
    int e0 = blockIdx.x * 2048;
    uint meta[8];
    #pragma unroll
    for (int i = 0; i < 8; ++i) {
        int e = e0 + i * 256 + tid;
        uint m = 0xFFFFFFFFu;
        if (e < N_EDGES) {
            int dst = ei[N_EDGES + e];
            int b = dst >> 8;
            int dl = dst & 255;
            int r = atomicAdd(&hist[b], 1);          // rank within block's chunk
            m = ((uint)b << 21) | ((uint)dl << 13) | (uint)r;   // r < 2048 < 2^13
        }
        meta[i] = m;
    }
    __syncthreads();
    for (int i = tid; i < NBKT; i += 256)
        base[i] = hist[i] ? atomicAdd(&bcnt[i], hist[i]) : 0;
    __syncthreads();
    #pragma unroll
    for (int i = 0; i < 8; ++i) {
        int e = e0 + i * 256 + tid;
        if (e < N_EDGES) {
            uint m = meta[i];
            int b = (int)(m >> 21);
            int dl = (int)((m >> 13) & 255);
            int r = (int)(m & 8191);
            int src = ei[e];
            int pos = base[b] + r;
            if (pos < BKT_CAP)
                bucket[(size_t)b * BKT_CAP + pos] = ((uint)dl << 16) | (uint)src;
        }
    }
}

// fused per-bucket histogram + in-block exclusive scan -> rowp partial, bsum
__global__ __launch_bounds__(256) void k_histscan(const int* __restrict__ bcnt,
                                                  const uint* __restrict__ bucket,
                                                  int* __restrict__ rowp,
                                                  int* __restrict__ bsum) {
    __shared__ int hist[256];
    __shared__ int s[256];
    int b = blockIdx.x, tid = threadIdx.x;
    hist[tid] = 0;
    __syncthreads();
    int n = bcnt[b]; if (n > BKT_CAP) n = BKT_CAP;
    for (int i = tid; i < n; i += 256)
        atomicAdd(&hist[(bucket[(size_t)b * BKT_CAP + i] >> 16) & 255], 1);
    __syncthreads();
    int v = hist[tid];
    s[tid] = v;
    __syncthreads();
    for (int off = 1; off < 256; off <<= 1) {
        int u = (tid >= off) ? s[tid - off] : 0;
        __syncthreads();
        s[tid] += u;
        __syncthreads();
    }
    int node = b * 256 + tid;
    if (node < N_NODES) rowp[node] = s[tid] - v;    // exclusive within bucket
    if (tid == 255) bsum[b] = s[255];
}

__global__ __launch_bounds__(256) void k_scan2(int* __restrict__ bsum, int nb) {
    __shared__ int s[256];
    int t = threadIdx.x;
    int v = (t < nb) ? bsum[t] : 0;
    s[t] = v;
    __syncthreads();
    for (int off = 1; off < 256; off <<= 1) {
        int u = (t >= off) ? s[t - off] : 0;
        __syncthreads();
        s[t] += u;
        __syncthreads();
    }
    if (t < nb) bsum[t] = s[t] - v;
}

__global__ __launch_bounds__(256) void k_scan3(int* __restrict__ rowp,
                                               const int* __restrict__ bsum) {
    int i = blockIdx.x * 256 + threadIdx.x;
    if (i < N_NODES) rowp[i] += bsum[blockIdx.x];
    if (i == 0) rowp[N_NODES] = N_EDGES;
}

// per-bucket counting sort -> colx (writes land in contiguous region)
__global__ __launch_bounds__(256) void k_sort(const int* __restrict__ bcnt,
                                              const uint* __restrict__ bucket,
                                              const int* __restrict__ rowp,
                                              int* __restrict__ colx) {
    __shared__ int fil[256];
    __shared__ int rp[256];
    int b = blockIdx.x, tid = threadIdx.x;
    fil[tid] = 0;
    int node = b * 256 + tid;
    rp[tid] = (node < N_NODES) ? rowp[node] : 0;
    __syncthreads();
    int n = bcnt[b]; if (n > BKT_CAP) n = BKT_CAP;
    for (int i = tid; i < n; i += 256) {
        uint w = bucket[(size_t)b * BKT_CAP + i];
        int dl = (int)((w >> 16) & 255);
        int src = (int)(w & 0xFFFF);
        int p = rp[dl] + atomicAdd(&fil[dl], 1);
        colx[p] = src;
    }
}

// -------- fused conversions: x -> bf16+fp8, W -> bf16, zero bcnt ------------
// blocks [0,6250): x float4 chunks; [6250,6314): W; block 6314: zero bcnt.

__global__ __launch_bounds__(256) void k_cvtall(const float* __restrict__ x,
                                                ushort* __restrict__ xb,
                                                uint* __restrict__ xq,
                                                const float* __restrict__ w0,
                                                const float* __restrict__ w1,
                                                const float* __restrict__ w2,
                                                const float* __restrict__ w3,
                                                ushort* o0, ushort* o1,
                                                ushort* o2, ushort* o3,
                                                int* __restrict__ bcnt) {
    int blk = blockIdx.x;
    int tid = threadIdx.x;
    if (blk < 6250) {
        int i = blk * 256 + tid;
        if (i >= (N_NODES * D) / 4) return;
        float4 v = ((const float4*)x)[i];
        ushort4 o;
        o.x = f2bf(v.x); o.y = f2bf(v.y); o.z = f2bf(v.z); o.w = f2bf(v.w);
        ((ushort4*)xb)[i] = o;
        int q = __builtin_amdgcn_cvt_pk_fp8_f32(v.x, v.y, 0, false);
        q = __builtin_amdgcn_cvt_pk_fp8_f32(v.z, v.w, q, true);
        xq[i] = (uint)q;
    } else if (blk < 6314) {
        int wb = blk - 6250;
        int b = wb >> 4;
        int i = (wb & 15) * 256 + tid;
        const float* in = (b == 0) ? w0 : (b == 1) ? w1 : (b == 2) ? w2 : w3;
        ushort*     out = (b == 0) ? o0 : (b == 1) ? o1 : (b == 2) ? o2 : o3;
        float4 v = ((const float4*)in)[i];
        ushort4 o;
        o.x = f2bf(v.x); o.y = f2bf(v.y); o.z = f2bf(v.z); o.w = f2bf(v.w);
        ((ushort4*)out)[i] = o;
    } else {
        bcnt[tid] = 0;      // 256 >= NBKT
    }
}

// ---------------- mean aggregation (fp8 gather, fp32 accum, bf16 out) --------
// 16 lanes/node: lanes 0-7 even neighbors, 8-15 odd; 16B (16 fp8)/lane. Unroll 4.

__device__ __forceinline__ void acc4(float* a, unsigned int word) {
    a[0] += __builtin_amdgcn_cvt_f32_fp8(word, 0);
    a[1] += __builtin_amdgcn_cvt_f32_fp8(word, 1);
    a[2] += __builtin_amdgcn_cvt_f32_fp8(word, 2);
    a[3] += __builtin_amdgcn_cvt_f32_fp8(word, 3);
}
__device__ __forceinline__ void acc16(float* a, uint4 v) {
    acc4(a + 0, v.x); acc4(a + 4, v.y); acc4(a + 8, v.z); acc4(a + 12, v.w);
}

__global__ __launch_bounds__(256) void k_agg(const uint* __restrict__ Xq,
                                             const int* __restrict__ rowp,
                                             const int* __restrict__ colx,
                                             ushort* __restrict__ Mb) {
    int t = blockIdx.x * 256 + threadIdx.x;
    int node = t >> 4;
    int sl = threadIdx.x & 7;           // 16B slot within 128B row
    int half = (threadIdx.x >> 3) & 1;  // even/odd neighbor stream
    if (node >= N_NODES) return;
    int beg = rowp[node], end = rowp[node + 1];
    float a[16];
    #pragma unroll
    for (int q = 0; q < 16; ++q) a[q] = 0.f;
    int j = beg + half;
    for (; j + 6 < end; j += 8) {                    // 4 edges per stream
        int s0 = colx[j], s1 = colx[j + 2], s2 = colx[j + 4], s3 = colx[j + 6];
        uint4 w0 = *(const uint4*)(Xq + (size_t)s0 * 32 + sl * 4);
        uint4 w1 = *(const uint4*)(Xq + (size_t)s1 * 32 + sl * 4);
        uint4 w2 = *(const uint4*)(Xq + (size_t)s2 * 32 + sl * 4);
        uint4 w3 = *(const uint4*)(Xq + (size_t)s3 * 32 + sl * 4);
        acc16(a, w0); acc16(a, w1); acc16(a, w2); acc16(a, w3);
    }
    for (; j < end; j += 2) {
        int s0 = colx[j];
        uint4 w0 = *(const uint4*)(Xq + (size_t)s0 * 32 + sl * 4);
        acc16(a, w0);
    }
    #pragma unroll
    for (int q = 0; q < 16; ++q) a[q] += __shfl_xor(a[q], 8, 64);
    if (half == 0) {
        float inv = 1.0f / fmaxf((float)(end - beg), 1.0f);
        bf16x8 o0, o1;
        #pragma unroll
        for (int q = 0; q < 8; ++q) o0[q] = (short)f2bf(a[q] * inv);
        #pragma unroll
        for (int q = 0; q < 8; ++q) o1[q] = (short)f2bf(a[q + 8] * inv);
        *(bf16x8*)(Mb + (size_t)node * D + sl * 16) = o0;
        *(bf16x8*)(Mb + (size_t)node * D + sl * 16 + 8) = o1;
    }
}

// ---------------- MFMA GEMM: W staged in swizzled LDS ----------------
// Wcat = [Wl | Wr] as [128 outcols][256 k'] bf16; swizzle byte ^= (row&7)<<4.
// A-frag: lane holds A[l&15][(l>>4)*8+j]; C/D: row=4*(l>>4)+i, col=16c+(l&15).
// mode 0: h1 = leaky(norm(.)) -> h1b (bf16) AND q_out (fp8, for L2 gather).
// mode 1: out = norm(.) + bf2f(h1b)  (fp32).

__global__ __launch_bounds__(256) void k_gemm(const ushort* __restrict__ Ab_m,
                                              const ushort* __restrict__ Ab_x,
                                              const ushort* __restrict__ Wl,
                                              const ushort* __restrict__ Wr,
                                              const float* __restrict__ bias,
                                              const ushort* __restrict__ h1b_in,
                                              float* __restrict__ out,
                                              ushort* __restrict__ h1b_out,
                                              unsigned char* __restrict__ q_out,
                                              int mode) {
    __shared__ ushort Wlds[32768];     // 64 KB
    int tid = threadIdx.x;

    #pragma unroll
    for (int jj = 0; jj < 16; ++jj) {
        int n = jj * 256 + tid;
        int row = n >> 5, c16 = n & 31;
        const ushort* src = (c16 < 16) ? (Wl + row * 128 + c16 * 8)
                                       : (Wr + row * 128 + (c16 - 16) * 8);
        bf16x8 v = *(const bf16x8*)src;
        int slot = row * 32 + (c16 ^ (row & 7));
        *(bf16x8*)(Wlds + slot * 8) = v;
    }
    __syncthreads();

    int lane = tid & 63;
    int wid = tid >> 6;
    int r = lane & 15, g = lane >> 4;
    int row0 = blockIdx.x * 64 + wid * 16;
    int anode = row0 + r;
    bool avalid = anode < N_NODES;
    const ushort* am = Ab_m + (size_t)anode * D + g * 8;
    const ushort* ax = Ab_x + (size_t)anode * D + g * 8;

    f32x4 acc[8];
    #pragma unroll
    for (int c = 0; c < 8; ++c) acc[c] = (f32x4){0.f, 0.f, 0.f, 0.f};

    #pragma unroll
    for (int s = 0; s < 8; ++s) {
        bf16x8 a = (bf16x8){0, 0, 0, 0, 0, 0, 0, 0};
        if (avalid) a = *(const bf16x8*)((s < 4 ? am : ax) + (s & 3) * 32);
        #pragma unroll
        for (int c = 0; c < 8; ++c) {
            int wrow = c * 16 + r;
            int byte = (wrow * 512 + s * 64 + g * 16) ^ ((wrow & 7) << 4);
            bf16x8 b = *(const bf16x8*)((const char*)Wlds + byte);
            acc[c] = __builtin_amdgcn_mfma_f32_16x16x32_bf16(a, b, acc[c], 0, 0, 0);
        }
    }

    #pragma unroll
    for (int c = 0; c < 8; ++c) {
        float bv = bias[c * 16 + r];
        #pragma unroll
        for (int i = 0; i < 4; ++i) acc[c][i] += bv;
    }

    float ss[4];
    #pragma unroll
    for (int i = 0; i < 4; ++i) {
        float s = 0.f;
        #pragma unroll
        for (int c = 0; c < 8; ++c) s += acc[c][i] * acc[c][i];
        ss[i] = s;
    }
    #pragma unroll
    for (int m = 1; m < 16; m <<= 1) {
        #pragma unroll
        for (int i = 0; i < 4; ++i) ss[i] += __shfl_xor(ss[i], m, 64);
    }
    float rn[4];
    #pragma unroll
    for (int i = 0; i < 4; ++i) rn[i] = 1.0f / fmaxf(sqrtf(ss[i]), 1e-12f);

    #pragma unroll
    for (int i = 0; i < 4; ++i) {
        int row = row0 + 4 * g + i;
        if (row >= N_NODES) continue;
        #pragma unroll
        for (int c = 0; c < 8; ++c) {
            int col = c * 16 + r;
            float v = acc[c][i] * rn[i];
            if (mode == 0) {
                v = (v > 0.f) ? v : 0.01f * v;               // leaky_relu
                h1b_out[(size_t)row * D + col] = f2bf(v);
                int qb = __builtin_amdgcn_cvt_pk_fp8_f32(v, v, 0, false);
                q_out[(size_t)row * D + col] = (unsigned char)(qb & 0xFF);
            } else {
                v += bf2f(h1b_in[(size_t)row * D + col]);     // h1 + h2
                out[(size_t)row * D + col] = v;
            }
        }
    }
}

// ---------------- launch ----------------

extern "C" void kernel_launch(void* const* d_in, const int* in_sizes, int n_in,
                              void* d_out, int out_size, void* d_ws, size_t ws_size,
                              hipStream_t stream) {
    const float* x   = (const float*)d_in[0];
    const int*   ei  = (const int*)d_in[1];   // int64 in ref, JAX x64-off => int32
    const float* W1l = (const float*)d_in[2];
    const float* b1l = (const float*)d_in[3];
    const float* W1r = (const float*)d_in[4];
    const float* W2l = (const float*)d_in[5];
    const float* b2l = (const float*)d_in[6];
    const float* W2r = (const float*)d_in[7];
    float* out = (float*)d_out;
    char*  ws  = (char*)d_ws;

    // workspace layout (bytes), total ~40 MB
    int*    bcnt = (int*)(ws + 0);              // 1024 B (zeroed by k_cvtall)
    int*    rowp = (int*)(ws + 204800);         // 200004
    int*    colx = (int*)(ws + 409600);         // 3.2 MB
    ushort* xb   = (ushort*)(ws + 3609600);     // 12.8 MB (becomes h1b after L1)
    ushort* Mb   = (ushort*)(ws + 16409600);    // 12.8 MB (mean buffer)
    ushort* Wb   = (ushort*)(ws + 29209600);    // 128 KB  (4x bf16 weights)
    ushort* W1lb = Wb;
    ushort* W1rb = Wb + 16384;
    ushort* W2lb = Wb + 32768;
    ushort* W2rb = Wb + 49152;
    int*    bsum = (int*)(ws + 29340672);       // 784 B (196 block sums)
    uint*   Q    = (uint*)(ws + 29341696);      // 6.4 MB fp8 table (x, then h1)
    uint*   bkt  = (uint*)(ws + 35742208);      // 4.0 MB bucket payload

    // fused: x->bf16+fp8, W->bf16, bcnt=0   (10 launches total this call)
    k_cvtall<<<6315, 256, 0, stream>>>(x, xb, Q, W1l, W1r, W2l, W2r,
                                       W1lb, W1rb, W2lb, W2rb, bcnt);

    const int NB = (N_NODES + 255) / 256;       // 196
    k_part<<<(N_EDGES + 2047) / 2048, 256, 0, stream>>>(ei, bcnt, bkt);
    k_histscan<<<NBKT, 256, 0, stream>>>(bcnt, bkt, rowp, bsum);
    k_scan2<<<1, 256, 0, stream>>>(bsum, NB);
    k_scan3<<<NB, 256, 0, stream>>>(rowp, bsum);
    k_sort<<<NBKT, 256, 0, stream>>>(bcnt, bkt, rowp, colx);

    const int NA = (N_NODES * 16 + 255) / 256;  // 3125
    // layer 1: gather x (fp8); h1 -> xb (bf16) + Q (fp8, epilogue-fused)
    k_agg <<<NA, 256, 0, stream>>>(Q, rowp, colx, Mb);
    k_gemm<<<(N_NODES + 63) / 64, 256, 0, stream>>>(Mb, xb, W1lb, W1rb, b1l,
                                                    nullptr, out, xb,
                                                    (unsigned char*)Q, 0);
    // layer 2: gather h1 (fp8); out = bf2f(h1b) + h2
    k_agg <<<NA, 256, 0, stream>>>(Q, rowp, colx, Mb);
    k_gemm<<<(N_NODES + 63) / 64, 256, 0, stream>>>(Mb, xb, W2lb, W2rb, b2l,
                                                    xb, out, nullptr,
                                                    nullptr, 1);
}